// Round 2
// baseline (152.650 us; speedup 1.0000x reference)
//
#include <hip/hip_runtime.h>
#include <math.h>

// GraphConvolution: out = segment_sum(edge_val * x[edge_col], edge_row) + x_0 + bias
// (Cayley transform in the reference is exactly identity => support == x.)
//
// Round 14: protect the x16 gather's L2 residency.
//   R13 analysis: the 42 us workspace re-poison fill is a fixed tax inside
//   the timed window; build's atomic chain is gone (~10 us) but spmm grew to
//   ~65 us because the 33.5 MB slot-scan (25% density) plus x0/out streams
//   evict x16 (8.4 MB vs 4 MiB per-XCD L2) during the gather phase.
//   - BBLK 256->128, CAP=16: lambda=7.6/cell (~lambda+3sigma), slists
//     33.5->16.8 MB at 50% density; ~400 overflow entries drained exactly.
//   - cnt_blk now p-major: spmm count stage reads 2 coalesced lines.
//   - __builtin_nontemporal_* on all zero-reuse streams (slist/cnt/x0 reads,
//     out writes, edge-array reads) so L2 keeps x16 (reused ~16x per row).

#define DFEAT 64
#define RPB   64            // rows per partition
#define NPART_MAX 1024
#define BBLK  128           // build blocks / chunks per partition
#define C_ROW 32            // per-row LDS bucket capacity
#define SPMM_T 512          // spmm block size (8 waves)

__device__ __forceinline__ int2 nt_load_int2(const int2* p) {
    unsigned long long v =
        __builtin_nontemporal_load((const unsigned long long*)p);
    int2 r;
    r.x = (int)(unsigned)(v & 0xFFFFFFFFull);
    r.y = (int)(unsigned)(v >> 32);
    return r;
}

// ---------------- Round-14 path (N <= 65536, N % 64 == 0) ------------------

__global__ void zero_ints_kernel(int* __restrict__ p, int n) {
    int i = blockIdx.x * blockDim.x + threadIdx.x;
    if (i < n) p[i] = 0;
}

// blocks [0, BBLK): deterministic chunked partition build (no global atomics)
// blocks [BBLK, BBLK+conv): RTN f32 -> bf16 conversion of x
__global__ __launch_bounds__(1024) void build_conv_kernel(
        const int* __restrict__ edge_row,
        const int* __restrict__ edge_col,
        const float* __restrict__ edge_val,
        const float* __restrict__ x,
        unsigned short* __restrict__ x16,
        int* __restrict__ cnt_blk,        // [NP][BBLK], p-major
        int2* __restrict__ slists,        // [NP][BBLK][CAP]
        int* __restrict__ ov_cursor,
        int2* __restrict__ ov_list,
        int E, int NP, int cap_shift, int n4) {
    __shared__ int cur[NPART_MAX];
    int t = threadIdx.x;

    if (blockIdx.x >= BBLK) {
        // ---- conversion role ----
        int i = (blockIdx.x - BBLK) * 1024 + t;
        if (i < n4) {
            float4 v = ((const float4*)x)[i];
            ushort4 o;
            unsigned u;
            u = __float_as_uint(v.x); o.x = (unsigned short)((u + 0x7FFFu + ((u >> 16) & 1u)) >> 16);
            u = __float_as_uint(v.y); o.y = (unsigned short)((u + 0x7FFFu + ((u >> 16) & 1u)) >> 16);
            u = __float_as_uint(v.z); o.z = (unsigned short)((u + 0x7FFFu + ((u >> 16) & 1u)) >> 16);
            u = __float_as_uint(v.w); o.w = (unsigned short)((u + 0x7FFFu + ((u >> 16) & 1u)) >> 16);
            ((ushort4*)x16)[i] = o;       // cached: warms L2 for spmm
        }
        return;
    }

    // ---- build role ----
    int b = blockIdx.x;
    int epb = (E + BBLK - 1) / BBLK;
    int base = b * epb;
    int end = base + epb; if (end > E) end = E;
    int CAP = 1 << cap_shift;

    for (int i = t; i < NP; i += 1024) cur[i] = 0;
    __syncthreads();

    for (int e = base + t; e < end; e += 1024) {
        int r = __builtin_nontemporal_load(&edge_row[e]);
        int c = __builtin_nontemporal_load(&edge_col[e]);
        float v = __builtin_nontemporal_load(&edge_val[e]);
        int p = r >> 6;
        int2 ent;
        ent.x = (int)(((unsigned)r << 16) | (unsigned)c);
        ent.y = __float_as_int(v);
        int pos = atomicAdd(&cur[p], 1);          // LDS only
        if (pos < CAP) {
            slists[((((size_t)p * BBLK) + b) << cap_shift) + pos] = ent;
        } else {
            int op = atomicAdd(ov_cursor, 1);     // ~400 entries expected
            ov_list[op] = ent;                    // capacity E: cannot overflow
        }
    }
    __syncthreads();
    for (int p = t; p < NP; p += 1024) {
        int c = cur[p];
        cnt_blk[(size_t)p * BBLK + b] = (c > CAP) ? CAP : c;
    }
}

// Block per partition: slot-scan bucketing + wave-per-row register spmm.
__global__ __launch_bounds__(SPMM_T) void spmm_fused_kernel(
        const unsigned short* __restrict__ x16,
        const float* __restrict__ x0,
        const float* __restrict__ bias,
        const int* __restrict__ cnt_blk,
        const int2* __restrict__ slists,
        int* __restrict__ ov_cursor,
        int2* __restrict__ ov_list,
        float* __restrict__ out, int NP, int cap_shift) {
    __shared__ int2 bkt[RPB * C_ROW];     // 16 KB
    __shared__ int  cur[RPB];
    __shared__ int  ccnt[BBLK];           // 512 B
    int p = blockIdx.x;
    int t = threadIdx.x;

    if (t < RPB) cur[t] = 0;
    if (t < BBLK)
        ccnt[t] = __builtin_nontemporal_load(&cnt_blk[(size_t)p * BBLK + t]);
    // zero-init buckets: padding entries (col 0, val 0) contribute nothing
    for (int i = t; i < RPB * C_ROW; i += SPMM_T) bkt[i] = make_int2(0, 0);
    __syncthreads();

    int CAP = 1 << cap_shift;
    int slots = BBLK << cap_shift;
    const int2* list = slists + (((size_t)p * BBLK) << cap_shift);
    for (int i = t; i < slots; i += SPMM_T) {
        int b = i >> cap_shift;
        int j = i & (CAP - 1);
        if (j < ccnt[b]) {
            int2 ent = nt_load_int2(&list[i]);    // streaming: don't pollute L2
            int row = (int)(((unsigned)ent.x >> 16) & (RPB - 1));
            int pos = atomicAdd(&cur[row], 1);    // native ds_add_u32
            if (pos < C_ROW) {
                bkt[row * C_ROW + pos] = ent;
            } else {
                int op = atomicAdd(ov_cursor, 1);
                ov_list[op] = ent;        // drained post-spmm
            }
        }
    }
    __syncthreads();

    int wave = t >> 6, lane = t & 63;
    float bl = bias[lane];
    for (int rr = wave; rr < RPB; rr += (SPMM_T / 64)) {
        int cr = cur[rr]; if (cr > C_ROW) cr = C_ROW;
        int cr8 = (cr + 7) & ~7;          // padded entries are zeros
        const int2* rb = &bkt[rr * C_ROW];
        float acc = 0.f;
        for (int j0 = 0; j0 < cr8; j0 += 8) {
            float xv[8], vv[8];
            #pragma unroll
            for (int k = 0; k < 8; k++) {
                int2 e = rb[j0 + k];      // LDS broadcast read
                vv[k] = __int_as_float(e.y);
                unsigned short hv =
                    x16[(size_t)((unsigned)e.x & 0xFFFFu) * DFEAT + lane];
                xv[k] = __uint_as_float((unsigned)hv << 16);
            }
            #pragma unroll
            for (int k = 0; k < 8; k++)
                acc += vv[k] * xv[k];
        }
        size_t go = (size_t)(p * RPB + rr) * DFEAT + lane;
        float x0v = __builtin_nontemporal_load(&x0[go]);
        __builtin_nontemporal_store(acc + x0v + bl, &out[go]);
    }
}

// Drain packed int2 overflow entries (~400 expected). Runs AFTER spmm.
__global__ void ov_drain_packed_kernel(const float* __restrict__ x,
                                       const int* __restrict__ ov_cursor,
                                       const int2* __restrict__ ov_list,
                                       float* __restrict__ out, int cap) {
    int n = ov_cursor[0];
    if (n > cap) n = cap;
    int wid = (blockIdx.x * blockDim.x + threadIdx.x) >> 6;
    int lane = threadIdx.x & 63;
    int nw = (gridDim.x * blockDim.x) >> 6;
    for (int k = wid; k < n; k += nw) {
        int2 p = ov_list[k];
        unsigned ux = (unsigned)p.x;
        int r = (int)(ux >> 16);
        int c = (int)(ux & 0xFFFFu);
        float v = __int_as_float(p.y);
        atomicAdd(&out[(size_t)r * DFEAT + lane],
                  v * x[(size_t)c * DFEAT + lane]);
    }
}

// ---------------- R7 single-phase path (general N; medium ws) ---------------

__global__ void bucket_scatter_kernel(const int* __restrict__ edge_row,
                                      const int* __restrict__ edge_col,
                                      const float* __restrict__ edge_val,
                                      int* __restrict__ cursor,
                                      int2* __restrict__ bucket,
                                      int* __restrict__ ov_cursor,
                                      int* __restrict__ ov_list,
                                      int E, int C) {
    int e = blockIdx.x * blockDim.x + threadIdx.x;
    if (e >= E) return;
    int r = edge_row[e];
    int pos = atomicAdd(&cursor[r], 1);
    if (pos < C) {
        int2 ent;
        ent.x = edge_col[e];
        ent.y = __float_as_int(edge_val[e]);
        bucket[(size_t)r * C + pos] = ent;
    } else {
        int op = atomicAdd(ov_cursor, 1);
        ov_list[op] = e;
    }
}

__global__ __launch_bounds__(256) void spmm_kernel(
        const float* __restrict__ x,
        const float* __restrict__ x0,
        const float* __restrict__ bias,
        const int* __restrict__ counts,
        const int2* __restrict__ bucket,
        float* __restrict__ out, int n, int C) {
    int wid = (blockIdx.x * blockDim.x + threadIdx.x) >> 6;
    int lane = threadIdx.x & 63;
    if (wid >= n) return;
    int cnt = counts[wid];
    if (cnt > C) cnt = C;
    const int2* bk = bucket + (size_t)wid * C;
    float acc = 0.f;
    for (int s0 = 0; s0 < cnt; s0 += 64) {
        int m = cnt - s0; if (m > 64) m = 64;
        int c = 0; float v = 0.f;
        if (lane < m) {
            int2 p = bk[s0 + lane];
            c = p.x;
            v = __int_as_float(p.y);
        }
        for (int j0 = 0; j0 < m; j0 += 8) {
            float xv[8], vv[8];
            #pragma unroll
            for (int k = 0; k < 8; k++) {
                int cj = __builtin_amdgcn_readlane(c, j0 + k);
                int vb = __builtin_amdgcn_readlane(__float_as_int(v), j0 + k);
                vv[k] = __int_as_float(vb);
                xv[k] = x[(size_t)cj * DFEAT + lane];
            }
            #pragma unroll
            for (int k = 0; k < 8; k++)
                acc += vv[k] * xv[k];
        }
    }
    out[(size_t)wid * DFEAT + lane] =
        acc + x0[(size_t)wid * DFEAT + lane] + bias[lane];
}

__global__ void ov_drain_id_kernel(const int* __restrict__ edge_row,
                                   const int* __restrict__ edge_col,
                                   const float* __restrict__ edge_val,
                                   const float* __restrict__ x,
                                   const int* __restrict__ ov_cursor,
                                   const int* __restrict__ ov_list,
                                   float* __restrict__ out, int E) {
    int n = ov_cursor[0];
    if (n > E) n = E;
    int wid = (blockIdx.x * blockDim.x + threadIdx.x) >> 6;
    int lane = threadIdx.x & 63;
    int nw = (gridDim.x * blockDim.x) >> 6;
    for (int k = wid; k < n; k += nw) {
        int e = ov_list[k];
        int r = edge_row[e], c = edge_col[e];
        float v = edge_val[e];
        atomicAdd(&out[(size_t)r * DFEAT + lane],
                  v * x[(size_t)c * DFEAT + lane]);
    }
}

// ---------------- last-resort fallback (round-1 structure) ------------------

__global__ void init_out_kernel(const float* __restrict__ x0,
                                const float* __restrict__ bias,
                                float* __restrict__ out, int n4) {
    int i = blockIdx.x * blockDim.x + threadIdx.x;
    if (i < n4) {
        float4 v = ((const float4*)x0)[i];
        int d = (i * 4) & (DFEAT - 1);
        v.x += bias[d + 0]; v.y += bias[d + 1];
        v.z += bias[d + 2]; v.w += bias[d + 3];
        ((float4*)out)[i] = v;
    }
}

__global__ void edge_scatter_kernel(const float* __restrict__ x,
                                    const float* __restrict__ edge_val,
                                    const int* __restrict__ edge_row,
                                    const int* __restrict__ edge_col,
                                    float* __restrict__ out, int E) {
    int tid = blockIdx.x * blockDim.x + threadIdx.x;
    int wave = tid >> 6, lane = tid & 63;
    int nwaves = (gridDim.x * blockDim.x) >> 6;
    for (int e = wave; e < E; e += nwaves) {
        int row = edge_row[e];
        int col = edge_col[e];
        float val = edge_val[e];
        atomicAdd(&out[row * DFEAT + lane], val * x[col * DFEAT + lane]);
    }
}

extern "C" void kernel_launch(void* const* d_in, const int* in_sizes, int n_in,
                              void* d_out, int out_size, void* d_ws, size_t ws_size,
                              hipStream_t stream) {
    const float* x    = (const float*)d_in[0];
    const float* x0   = (const float*)d_in[1];
    const float* ev   = (const float*)d_in[2];
    // d_in[3] = weight: unused (Cayley == identity)
    const float* bias = (const float*)d_in[4];
    const int*   er   = (const int*)d_in[5];
    const int*   ec   = (const int*)d_in[6];
    float* out = (float*)d_out;

    int E = in_sizes[2];
    int N = out_size / DFEAT;

    auto align256 = [](size_t b) { return (b + 255) & ~size_t(255); };

    // ---- Round-14 path ----
    if (N <= 65536 && N % RPB == 0 && E > 0) {
        int NP = N / RPB;                       // partitions (<= 1024)
        double lam = (double)E / ((double)NP * (double)BBLK);
        double want = lam + 3.0 * sqrt(lam > 1.0 ? lam : 1.0);
        int cap_shift = 4;                      // CAP >= 16
        while ((double)(1 << cap_shift) < want && cap_shift < 10) cap_shift++;
        size_t CAP = (size_t)1 << cap_shift;

        size_t ovc_b  = 256;
        size_t x16_b  = align256((size_t)N * DFEAT * 2);
        size_t ov_b   = align256((size_t)E * 8);
        size_t cnt_b  = align256((size_t)BBLK * (size_t)NP * 4);
        size_t sl_b   = align256((size_t)NP * BBLK * CAP * 8);
        size_t total  = ovc_b + x16_b + ov_b + cnt_b + sl_b;

        if (total <= ws_size) {
            char* ws = (char*)d_ws;
            int*            ovc     = (int*)ws;
            unsigned short* x16     = (unsigned short*)(ws + ovc_b);
            int2*           ov_list = (int2*)(ws + ovc_b + x16_b);
            int*            cnt_blk = (int*)(ws + ovc_b + x16_b + ov_b);
            int2*           slists  = (int2*)(ws + ovc_b + x16_b + ov_b + cnt_b);

            zero_ints_kernel<<<1, 64, 0, stream>>>(ovc, 64);
            int n4 = N * DFEAT / 4;
            int conv_blocks = (n4 + 1023) / 1024;
            build_conv_kernel<<<BBLK + conv_blocks, 1024, 0, stream>>>(
                er, ec, ev, x, x16, cnt_blk, slists, ovc, ov_list,
                E, NP, cap_shift, n4);
            spmm_fused_kernel<<<NP, SPMM_T, 0, stream>>>(
                x16, x0, bias, cnt_blk, slists, ovc, ov_list, out, NP, cap_shift);
            ov_drain_packed_kernel<<<64, 256, 0, stream>>>(
                x, ovc, ov_list, out, E);
            return;
        }
    }

    // ---- R7 single-phase path ----
    {
        size_t cur_b = align256((size_t)N * 4);
        size_t ovc_b = 256;
        size_t ov_b  = align256((size_t)E * 4);
        size_t fixed = cur_b + ovc_b + ov_b;
        int C = 0;
        if (ws_size > fixed) {
            long long cmax = (long long)((ws_size - fixed) / ((size_t)N * 8));
            for (int cand : {64, 48, 40, 32, 28, 24})
                if (cmax >= cand) { C = cand; break; }
        }
        if (C >= 24) {
            char* ws = (char*)d_ws;
            int*  cursor  = (int*)ws;
            int*  ovc     = (int*)(ws + cur_b);
            int*  ov_list = (int*)(ws + cur_b + ovc_b);
            int2* bucket  = (int2*)(ws + fixed);

            int nzero = (int)((cur_b + ovc_b) / 4);
            zero_ints_kernel<<<(nzero + 255) / 256, 256, 0, stream>>>(cursor, nzero);
            bucket_scatter_kernel<<<(E + 255) / 256, 256, 0, stream>>>(
                er, ec, ev, cursor, bucket, ovc, ov_list, E, C);
            int blocks = (N * 64 + 255) / 256;
            spmm_kernel<<<blocks, 256, 0, stream>>>(
                x, x0, bias, cursor, bucket, out, N, C);
            ov_drain_id_kernel<<<64, 256, 0, stream>>>(
                er, ec, ev, x, ovc, ov_list, out, E);
            return;
        }
    }

    // ---- last resort: atomic scatter ----
    int n4 = out_size / 4;
    init_out_kernel<<<(n4 + 255) / 256, 256, 0, stream>>>(x0, bias, out, n4);
    edge_scatter_kernel<<<8192, 256, 0, stream>>>(x, ev, er, ec, out, E);
}

// Round 3
// 145.236 us; speedup vs baseline: 1.0510x; 1.0510x over previous
//
#include <hip/hip_runtime.h>
#include <math.h>

// GraphConvolution: out = segment_sum(edge_val * x[edge_col], edge_row) + x_0 + bias
// (Cayley transform in the reference is exactly identity => support == x.)
//
// Round 15: write-combined build scatter + embedded counts.
//   R12 post-mortem: build's WRITE_SIZE was 41 MB for an 8 MB payload --
//   random 8-B stores write-allocate lines that evict half-empty (~1 TB/s
//   effective). That, not the atomic chain, co-limited build; R13's atomic
//   fix therefore bought ~nothing. This round:
//   - Build stages edges in LDS: 1024 cells (one per partition) x 64 B,
//     slot 0 = count word, CAP=7 entries (lambda=2, ~630 overflow edges,
//     exactly drained). After sync, cells flush as FULL coalesced lines.
//   - Partitions paired 2-per-128B-line so each line is written by exactly
//     one block (no cross-XCD half-line sharing); spmm partner blocks share
//     the fetched line in L2.
//   - Counts embedded in cells: cnt_blk array and its traffic deleted.
//   - spmm: two-subpass scan (counts, then entries -- same lines, L2-hot);
//     gather batch 8 -> 16 (halved latency chain per row).
//   - All R14 nontemporal hints reverted (regression).
//   - Dispatches 5 -> 4: zero(1.5K ints), build_conv, spmm, drain.

#define DFEAT 64
#define RPB   64            // rows per partition
#define NPART_MAX 1024
#define BBLK  512           // build blocks == cells per partition
#define BUILD_T 512
#define CAPC  7             // entries per cell (slot 0 holds the count)
#define C_ROW 32            // per-row LDS bucket capacity in spmm
#define SPMM_T 512          // spmm block size (8 waves)

// ---------------- Round-15 path (N <= 65536, N % 64 == 0) ------------------

__global__ void zero_ints_kernel(int* __restrict__ p, int n) {
    int i = blockIdx.x * blockDim.x + threadIdx.x;
    if (i < n) p[i] = 0;
}

// blocks [0, BBLK): LDS write-combined partition build
// blocks [BBLK, grid): RTN f32 -> bf16 conversion of x (grid-stride)
__global__ __launch_bounds__(BUILD_T) void build_conv_kernel(
        const int* __restrict__ edge_row,
        const int* __restrict__ edge_col,
        const float* __restrict__ edge_val,
        const float* __restrict__ x,
        unsigned short* __restrict__ x16,
        int2* __restrict__ slists,        // [NP/2][BBLK][2 cells][8 int2]
        int* __restrict__ ov_cnt,        // [BBLK + NP], pre-zeroed
        int2* __restrict__ ov,           // [BBLK + NP][OVS]
        int E, int NP, int OVS, int n4) {
    __shared__ int2 cell[NPART_MAX * 8];   // 64 KB: cell p = [p*8 .. p*8+8)
    int t = threadIdx.x;

    if (blockIdx.x >= BBLK) {
        // ---- conversion role ----
        int stride = (gridDim.x - BBLK) * BUILD_T;
        for (int i = (blockIdx.x - BBLK) * BUILD_T + t; i < n4; i += stride) {
            float4 v = ((const float4*)x)[i];
            ushort4 o;
            unsigned u;
            u = __float_as_uint(v.x); o.x = (unsigned short)((u + 0x7FFFu + ((u >> 16) & 1u)) >> 16);
            u = __float_as_uint(v.y); o.y = (unsigned short)((u + 0x7FFFu + ((u >> 16) & 1u)) >> 16);
            u = __float_as_uint(v.z); o.z = (unsigned short)((u + 0x7FFFu + ((u >> 16) & 1u)) >> 16);
            u = __float_as_uint(v.w); o.w = (unsigned short)((u + 0x7FFFu + ((u >> 16) & 1u)) >> 16);
            ((ushort4*)x16)[i] = o;       // cached: warms L2/L3 for spmm
        }
        return;
    }

    // ---- build role ----
    int b = blockIdx.x;
    for (int p = t; p < NP; p += BUILD_T) cell[p * 8].x = 0;   // count words
    __syncthreads();

    int epb = (E + BBLK - 1) / BBLK;
    int base = b * epb;
    int end = base + epb; if (end > E) end = E;

    for (int e = base + t; e < end; e += BUILD_T) {
        int r = edge_row[e];
        int c = edge_col[e];
        float v = edge_val[e];
        int p = r >> 6;
        int2 ent;
        ent.x = (int)(((unsigned)r << 16) | (unsigned)c);
        ent.y = __float_as_int(v);
        int pos = atomicAdd(&cell[p * 8].x, 1);   // LDS
        if (pos < CAPC) {
            cell[p * 8 + 1 + pos] = ent;
        } else {
            int g = atomicAdd(&ov_cnt[b], 1);     // rare (~630 total)
            ov[(size_t)b * OVS + g] = ent;        // OVS >= epb: cannot lose
        }
    }
    __syncthreads();
    for (int p = t; p < NP; p += BUILD_T) {
        if (cell[p * 8].x > CAPC) cell[p * 8].x = CAPC;
    }
    __syncthreads();
    // flush: full 128-B lines; line (p>>1, b) holds cells of partitions
    // 2*(p>>1) and 2*(p>>1)+1 -- both from THIS block.
    {
        int4* g4 = (int4*)slists;
        const int4* l4 = (const int4*)cell;
        for (int i = t; i < NP * 4; i += BUILD_T) {
            int p = i >> 2, q = i & 3;
            size_t gi = ((size_t)(unsigned)(p >> 1) * BBLK + (unsigned)b) * 8
                      + (size_t)(unsigned)((p & 1) * 4 + q);
            g4[gi] = l4[p * 4 + q];
        }
    }
}

// Block per partition: two-subpass slot scan + wave-per-row register spmm.
__global__ __launch_bounds__(SPMM_T) void spmm_fused_kernel(
        const unsigned short* __restrict__ x16,
        const float* __restrict__ x0,
        const float* __restrict__ bias,
        const int2* __restrict__ slists,
        int* __restrict__ ov_cnt,
        int2* __restrict__ ov,
        float* __restrict__ out, int NP, int OVS) {
    __shared__ int2 bkt[RPB * C_ROW];     // 16 KB
    __shared__ int  cur[RPB];
    __shared__ int  ccnt[BBLK];           // 2 KB
    int p = blockIdx.x;
    int t = threadIdx.x;

    if (t < RPB) cur[t] = 0;
    for (int i = t; i < RPB * C_ROW; i += SPMM_T) bkt[i] = make_int2(0, 0);

    // cell (p, b) starts at int2 offset pb + b*16
    size_t pb = ((size_t)(unsigned)(p >> 1) * BBLK) * 16 + (size_t)(p & 1) * 8;
    const int* s32 = (const int*)slists;
    for (int b = t; b < BBLK; b += SPMM_T)
        ccnt[b] = s32[(pb + (size_t)b * 16) * 2];   // count word (<= CAPC)
    __syncthreads();

    for (int i = t; i < BBLK * 8; i += SPMM_T) {
        int b = i >> 3, j = i & 7;
        if (j >= 1 && j <= ccnt[b]) {
            int2 ent = slists[pb + (size_t)b * 16 + j];  // L2-hot line
            int row = (int)(((unsigned)ent.x >> 16) & (RPB - 1));
            int pos = atomicAdd(&cur[row], 1);           // ds_add
            if (pos < C_ROW) {
                bkt[row * C_ROW + pos] = ent;
            } else {
                int g = atomicAdd(&ov_cnt[BBLK + p], 1); // rare
                ov[(size_t)(BBLK + p) * OVS + g] = ent;  // OVS >= BBLK*8
            }
        }
    }
    __syncthreads();

    int wave = t >> 6, lane = t & 63;
    float bl = bias[lane];
    for (int rr = wave; rr < RPB; rr += (SPMM_T / 64)) {
        int cr = cur[rr]; if (cr > C_ROW) cr = C_ROW;
        int cr16 = (cr + 15) & ~15;       // padded entries are zeros
        const int2* rb = &bkt[rr * C_ROW];
        float acc = 0.f;
        for (int j0 = 0; j0 < cr16; j0 += 16) {
            float xv[16], vv[16];
            #pragma unroll
            for (int k = 0; k < 16; k++) {
                int2 e = rb[j0 + k];      // LDS broadcast read
                vv[k] = __int_as_float(e.y);
                unsigned short hv =
                    x16[(size_t)((unsigned)e.x & 0xFFFFu) * DFEAT + lane];
                xv[k] = __uint_as_float((unsigned)hv << 16);
            }
            #pragma unroll
            for (int k = 0; k < 16; k++)
                acc += vv[k] * xv[k];
        }
        size_t go = (size_t)(p * RPB + rr) * DFEAT + lane;
        out[go] = acc + x0[go] + bl;      // coalesced 256 B row store
    }
}

// Drain per-region overflow lists with full-precision f32 x. Runs AFTER spmm.
__global__ void ov_drain_kernel(const float* __restrict__ x,
                                const int* __restrict__ ov_cnt,
                                const int2* __restrict__ ov,
                                float* __restrict__ out,
                                int REGIONS, int OVS) {
    int wid = (blockIdx.x * blockDim.x + threadIdx.x) >> 6;
    int lane = threadIdx.x & 63;
    int nw = (gridDim.x * blockDim.x) >> 6;
    for (int reg = wid; reg < REGIONS; reg += nw) {
        int n = ov_cnt[reg];
        if (n > OVS) n = OVS;
        for (int k = 0; k < n; k++) {
            int2 pk = ov[(size_t)reg * OVS + k];
            unsigned ux = (unsigned)pk.x;
            int r = (int)(ux >> 16);
            int c = (int)(ux & 0xFFFFu);
            float v = __int_as_float(pk.y);
            atomicAdd(&out[(size_t)r * DFEAT + lane],
                      v * x[(size_t)c * DFEAT + lane]);
        }
    }
}

// ---------------- R7 single-phase path (general N; medium ws) ---------------

__global__ void bucket_scatter_kernel(const int* __restrict__ edge_row,
                                      const int* __restrict__ edge_col,
                                      const float* __restrict__ edge_val,
                                      int* __restrict__ cursor,
                                      int2* __restrict__ bucket,
                                      int* __restrict__ ov_cursor,
                                      int* __restrict__ ov_list,
                                      int E, int C) {
    int e = blockIdx.x * blockDim.x + threadIdx.x;
    if (e >= E) return;
    int r = edge_row[e];
    int pos = atomicAdd(&cursor[r], 1);
    if (pos < C) {
        int2 ent;
        ent.x = edge_col[e];
        ent.y = __float_as_int(edge_val[e]);
        bucket[(size_t)r * C + pos] = ent;
    } else {
        int op = atomicAdd(ov_cursor, 1);
        ov_list[op] = e;
    }
}

__global__ __launch_bounds__(256) void spmm_kernel(
        const float* __restrict__ x,
        const float* __restrict__ x0,
        const float* __restrict__ bias,
        const int* __restrict__ counts,
        const int2* __restrict__ bucket,
        float* __restrict__ out, int n, int C) {
    int wid = (blockIdx.x * blockDim.x + threadIdx.x) >> 6;
    int lane = threadIdx.x & 63;
    if (wid >= n) return;
    int cnt = counts[wid];
    if (cnt > C) cnt = C;
    const int2* bk = bucket + (size_t)wid * C;
    float acc = 0.f;
    for (int s0 = 0; s0 < cnt; s0 += 64) {
        int m = cnt - s0; if (m > 64) m = 64;
        int c = 0; float v = 0.f;
        if (lane < m) {
            int2 p = bk[s0 + lane];
            c = p.x;
            v = __int_as_float(p.y);
        }
        for (int j0 = 0; j0 < m; j0 += 8) {
            float xv[8], vv[8];
            #pragma unroll
            for (int k = 0; k < 8; k++) {
                int cj = __builtin_amdgcn_readlane(c, j0 + k);
                int vb = __builtin_amdgcn_readlane(__float_as_int(v), j0 + k);
                vv[k] = __int_as_float(vb);
                xv[k] = x[(size_t)cj * DFEAT + lane];
            }
            #pragma unroll
            for (int k = 0; k < 8; k++)
                acc += vv[k] * xv[k];
        }
    }
    out[(size_t)wid * DFEAT + lane] =
        acc + x0[(size_t)wid * DFEAT + lane] + bias[lane];
}

__global__ void ov_drain_id_kernel(const int* __restrict__ edge_row,
                                   const int* __restrict__ edge_col,
                                   const float* __restrict__ edge_val,
                                   const float* __restrict__ x,
                                   const int* __restrict__ ov_cursor,
                                   const int* __restrict__ ov_list,
                                   float* __restrict__ out, int E) {
    int n = ov_cursor[0];
    if (n > E) n = E;
    int wid = (blockIdx.x * blockDim.x + threadIdx.x) >> 6;
    int lane = threadIdx.x & 63;
    int nw = (gridDim.x * blockDim.x) >> 6;
    for (int k = wid; k < n; k += nw) {
        int e = ov_list[k];
        int r = edge_row[e], c = edge_col[e];
        float v = edge_val[e];
        atomicAdd(&out[(size_t)r * DFEAT + lane],
                  v * x[(size_t)c * DFEAT + lane]);
    }
}

// ---------------- last-resort fallback (round-1 structure) ------------------

__global__ void init_out_kernel(const float* __restrict__ x0,
                                const float* __restrict__ bias,
                                float* __restrict__ out, int n4) {
    int i = blockIdx.x * blockDim.x + threadIdx.x;
    if (i < n4) {
        float4 v = ((const float4*)x0)[i];
        int d = (i * 4) & (DFEAT - 1);
        v.x += bias[d + 0]; v.y += bias[d + 1];
        v.z += bias[d + 2]; v.w += bias[d + 3];
        ((float4*)out)[i] = v;
    }
}

__global__ void edge_scatter_kernel(const float* __restrict__ x,
                                    const float* __restrict__ edge_val,
                                    const int* __restrict__ edge_row,
                                    const int* __restrict__ edge_col,
                                    float* __restrict__ out, int E) {
    int tid = blockIdx.x * blockDim.x + threadIdx.x;
    int wave = tid >> 6, lane = tid & 63;
    int nwaves = (gridDim.x * blockDim.x) >> 6;
    for (int e = wave; e < E; e += nwaves) {
        int row = edge_row[e];
        int col = edge_col[e];
        float val = edge_val[e];
        atomicAdd(&out[row * DFEAT + lane], val * x[col * DFEAT + lane]);
    }
}

extern "C" void kernel_launch(void* const* d_in, const int* in_sizes, int n_in,
                              void* d_out, int out_size, void* d_ws, size_t ws_size,
                              hipStream_t stream) {
    const float* x    = (const float*)d_in[0];
    const float* x0   = (const float*)d_in[1];
    const float* ev   = (const float*)d_in[2];
    // d_in[3] = weight: unused (Cayley == identity)
    const float* bias = (const float*)d_in[4];
    const int*   er   = (const int*)d_in[5];
    const int*   ec   = (const int*)d_in[6];
    float* out = (float*)d_out;

    int E = in_sizes[2];
    int N = out_size / DFEAT;

    auto align256 = [](size_t b) { return (b + 255) & ~size_t(255); };

    // ---- Round-15 path ----
    if (N <= 65536 && N % RPB == 0 && E > 0) {
        int NP = N / RPB;                       // partitions (<= 1024)
        int REGIONS = BBLK + NP;
        int epb = (E + BBLK - 1) / BBLK;
        int OVS = epb > (BBLK * 8) ? epb : (BBLK * 8);   // worst-case safe

        size_t ovc_b  = align256((size_t)REGIONS * 4);
        size_t x16_b  = align256((size_t)N * DFEAT * 2);
        size_t ov_b   = align256((size_t)REGIONS * (size_t)OVS * 8);
        size_t sl_b   = align256((size_t)NP * BBLK * 8 * 8);
        size_t total  = ovc_b + x16_b + ov_b + sl_b;

        if (total <= ws_size) {
            char* ws = (char*)d_ws;
            int*            ovc    = (int*)ws;
            unsigned short* x16    = (unsigned short*)(ws + ovc_b);
            int2*           ovl    = (int2*)(ws + ovc_b + x16_b);
            int2*           slists = (int2*)(ws + ovc_b + x16_b + ov_b);

            zero_ints_kernel<<<(REGIONS + 255) / 256, 256, 0, stream>>>(
                ovc, REGIONS);
            int n4 = N * DFEAT / 4;
            int conv_blocks = 512;
            build_conv_kernel<<<BBLK + conv_blocks, BUILD_T, 0, stream>>>(
                er, ec, ev, x, x16, slists, ovc, ovl, E, NP, OVS, n4);
            spmm_fused_kernel<<<NP, SPMM_T, 0, stream>>>(
                x16, x0, bias, slists, ovc, ovl, out, NP, OVS);
            ov_drain_kernel<<<64, 256, 0, stream>>>(
                x, ovc, ovl, out, REGIONS, OVS);
            return;
        }
    }

    // ---- R7 single-phase path ----
    {
        size_t cur_b = align256((size_t)N * 4);
        size_t ovc_b = 256;
        size_t ov_b  = align256((size_t)E * 4);
        size_t fixed = cur_b + ovc_b + ov_b;
        int C = 0;
        if (ws_size > fixed) {
            long long cmax = (long long)((ws_size - fixed) / ((size_t)N * 8));
            for (int cand : {64, 48, 40, 32, 28, 24})
                if (cmax >= cand) { C = cand; break; }
        }
        if (C >= 24) {
            char* ws = (char*)d_ws;
            int*  cursor  = (int*)ws;
            int*  ovc     = (int*)(ws + cur_b);
            int*  ov_list = (int*)(ws + cur_b + ovc_b);
            int2* bucket  = (int2*)(ws + fixed);

            int nzero = (int)((cur_b + ovc_b) / 4);
            zero_ints_kernel<<<(nzero + 255) / 256, 256, 0, stream>>>(cursor, nzero);
            bucket_scatter_kernel<<<(E + 255) / 256, 256, 0, stream>>>(
                er, ec, ev, cursor, bucket, ovc, ov_list, E, C);
            int blocks = (N * 64 + 255) / 256;
            spmm_kernel<<<blocks, 256, 0, stream>>>(
                x, x0, bias, cursor, bucket, out, N, C);
            ov_drain_id_kernel<<<64, 256, 0, stream>>>(
                er, ec, ev, x, ovc, ov_list, out, E);
            return;
        }
    }

    // ---- last resort: atomic scatter ----
    int n4 = out_size / 4;
    init_out_kernel<<<(n4 + 255) / 256, 256, 0, stream>>>(x0, bias, out, n4);
    edge_scatter_kernel<<<8192, 256, 0, stream>>>(x, ev, er, ec, out, E);
}

// Round 4
// 138.379 us; speedup vs baseline: 1.1031x; 1.0496x over previous
//
#include <hip/hip_runtime.h>
#include <math.h>

// GraphConvolution: out = segment_sum(edge_val * x[edge_col], edge_row) + x_0 + bias
// (Cayley transform in the reference is exactly identity => support == x.)
//
// Round 16: density + latency-cover.
//   R15 counters: spmm 44 us, FETCH 109 MB (slists 32 + x0 17 + x16-miss ~60
//   compulsory), VALUBusy 37%, VGPR=28 -> the 16-gather batch was NOT in
//   flight (needs >32 VGPRs); gathers serialize.
//   - BBLK 512->128, 128-B cells (slot0=count, 15 entries, lambda=7.6,
//     density 48%): slists 32->16.8 MB; spmm reads one contiguous 16 KB
//     stream per partition. ~2K overflow edges, exactly drained.
//   - Build: 128 blocks x 1024 thr, dynamic LDS (NP*128 + (NP+16)*4 B).
//     Discriminating test for the persistent ~40 us build cost.
//   - spmm: 2 rows per wave with interleaved batch-8 gathers -> ~16
//     independent loads in flight (~56 VGPR, still 32 waves/CU).
//   - Overflow counters in LDS, stored once by owner block: no pre-zeroed
//     globals -> zero-kernel deleted. Dispatches 5 -> 4.

#define DFEAT 64
#define RPB   64            // rows per partition
#define NPART_MAX 1024
#define BBLK  128           // build blocks == cells per partition
#define BUILD_T 1024
#define CONV_BLK 256
#define CAPC  15            // entries per cell (slot 0 holds the count)
#define CELL_I2 16          // int2 per cell (128 B)
#define C_ROW 32            // per-row LDS bucket capacity in spmm
#define SPMM_T 512          // spmm block size (8 waves)
#define OVS_S 2048          // spmm per-partition overflow capacity (>=128*15)

// ---------------- Round-16 path (N <= 65536, N % 64 == 0) ------------------

__global__ void zero_ints_kernel(int* __restrict__ p, int n) {
    int i = blockIdx.x * blockDim.x + threadIdx.x;
    if (i < n) p[i] = 0;
}

// blocks [0, BBLK): LDS-staged partition build (dynamic LDS)
// blocks [BBLK, BBLK+CONV_BLK): RTN f32 -> bf16 conversion of x
__global__ __launch_bounds__(BUILD_T) void build_conv_kernel(
        const int* __restrict__ edge_row,
        const int* __restrict__ edge_col,
        const float* __restrict__ edge_val,
        const float* __restrict__ x,
        unsigned short* __restrict__ x16,
        int2* __restrict__ slists,        // [NP][BBLK][CELL_I2] p-major
        int* __restrict__ ov_cnt,        // [BBLK + NP] (no pre-zero needed)
        int2* __restrict__ ov,           // build regions: [BBLK][epb]
        int E, int NP, int epb, int n4) {
    int t = threadIdx.x;

    if (blockIdx.x >= BBLK) {
        // ---- conversion role ----
        int stride = CONV_BLK * BUILD_T;
        for (int i = (blockIdx.x - BBLK) * BUILD_T + t; i < n4; i += stride) {
            float4 v = ((const float4*)x)[i];
            ushort4 o;
            unsigned u;
            u = __float_as_uint(v.x); o.x = (unsigned short)((u + 0x7FFFu + ((u >> 16) & 1u)) >> 16);
            u = __float_as_uint(v.y); o.y = (unsigned short)((u + 0x7FFFu + ((u >> 16) & 1u)) >> 16);
            u = __float_as_uint(v.z); o.z = (unsigned short)((u + 0x7FFFu + ((u >> 16) & 1u)) >> 16);
            u = __float_as_uint(v.w); o.w = (unsigned short)((u + 0x7FFFu + ((u >> 16) & 1u)) >> 16);
            ((ushort4*)x16)[i] = o;       // cached: warms L2/L3 for spmm
        }
        return;
    }

    // ---- build role ----
    extern __shared__ char smem[];
    int2* cell = (int2*)smem;                           // NP * CELL_I2
    int*  cnt  = (int*)(smem + (size_t)NP * 128);       // NP + 1 (ov counter)

    int b = blockIdx.x;
    for (int i = t; i < NP + 1; i += BUILD_T) cnt[i] = 0;
    __syncthreads();

    int base = b * epb;
    int end = base + epb; if (end > E) end = E;

    for (int e = base + t; e < end; e += BUILD_T) {
        int r = edge_row[e];
        int c = edge_col[e];
        float v = edge_val[e];
        int p = r >> 6;
        int2 ent;
        ent.x = (int)(((unsigned)r << 16) | (unsigned)c);
        ent.y = __float_as_int(v);
        int pos = atomicAdd(&cnt[p], 1);          // LDS
        if (pos < CAPC) {
            cell[p * CELL_I2 + 1 + pos] = ent;
        } else {
            int op = atomicAdd(&cnt[NP], 1);      // rare (~2K total)
            ov[(size_t)b * epb + op] = ent;       // op < edges-in-block <= epb
        }
    }
    __syncthreads();
    for (int p = t; p < NP; p += BUILD_T) {
        int cc = cnt[p];
        cell[p * CELL_I2].x = (cc > CAPC) ? CAPC : cc;
    }
    __syncthreads();
    // flush: full 128-B cells; slists p-major => spmm reads 16 KB streams.
    {
        int4* g4 = (int4*)slists;
        const int4* l4 = (const int4*)cell;
        for (int i = t; i < NP * 8; i += BUILD_T) {
            int p = i >> 3, q = i & 7;
            g4[((size_t)p * BBLK + (unsigned)b) * 8 + q] = l4[i];
        }
    }
    if (t == 0) ov_cnt[b] = cnt[NP];
}

// Block per partition: contiguous slot scan + 2-row-per-wave register spmm.
__global__ __launch_bounds__(SPMM_T) void spmm_fused_kernel(
        const unsigned short* __restrict__ x16,
        const float* __restrict__ x0,
        const float* __restrict__ bias,
        const int2* __restrict__ slists,
        int* __restrict__ ov_cnt,
        int2* __restrict__ ov,           // spmm regions at BBLK*epb
        float* __restrict__ out, int NP, int epb) {
    __shared__ int2 bkt[RPB * C_ROW];     // 16 KB
    __shared__ int  cur[RPB];
    __shared__ int  ccnt[BBLK];           // 512 B
    __shared__ int  s_ov;
    int p = blockIdx.x;
    int t = threadIdx.x;

    if (t < RPB) cur[t] = 0;
    if (t == SPMM_T - 1) s_ov = 0;
    // zero-init buckets: padded slots (col 0, val 0) contribute nothing
    for (int i = t; i < RPB * C_ROW; i += SPMM_T) bkt[i] = make_int2(0, 0);

    const int2* list = slists + (size_t)p * BBLK * CELL_I2;
    if (t < BBLK)
        ccnt[t] = ((const int*)list)[t * CELL_I2 * 2];   // slot0.x (<= CAPC)
    __syncthreads();

    for (int i = t; i < BBLK * CELL_I2; i += SPMM_T) {
        int b = i >> 4, j = i & 15;
        if (j >= 1 && j <= ccnt[b]) {
            int2 ent = list[i];                  // contiguous, L2-hot line
            int row = (int)(((unsigned)ent.x >> 16) & (RPB - 1));
            int pos = atomicAdd(&cur[row], 1);   // ds_add
            if (pos < C_ROW) {
                bkt[row * C_ROW + pos] = ent;
            } else {
                int op = atomicAdd(&s_ov, 1);    // bounded by 128*15 < OVS_S
                ov[(size_t)BBLK * epb + (size_t)p * OVS_S + op] = ent;
            }
        }
    }
    __syncthreads();
    if (t == 0) ov_cnt[BBLK + p] = s_ov;

    int wave = t >> 6, lane = t & 63;
    float bl = bias[lane];
    for (int g = 0; g < 4; g++) {
        int rA = g * 16 + wave;
        int rB = rA + 8;
        int crA = cur[rA] > C_ROW ? C_ROW : cur[rA];
        int crB = cur[rB] > C_ROW ? C_ROW : cur[rB];
        int mA = (crA + 7) & ~7, mB = (crB + 7) & ~7;
        int m = mA > mB ? mA : mB;               // padded slots are zeros
        const int2* ra = &bkt[rA * C_ROW];
        const int2* rb2 = &bkt[rB * C_ROW];
        float accA = 0.f, accB = 0.f;
        for (int j0 = 0; j0 < m; j0 += 8) {
            float xa[8], va[8], xb[8], vb[8];
            #pragma unroll
            for (int k = 0; k < 8; k++) {        // 16 independent gathers
                int2 ea = ra[j0 + k];
                int2 eb = rb2[j0 + k];
                va[k] = __int_as_float(ea.y);
                vb[k] = __int_as_float(eb.y);
                xa[k] = __uint_as_float((unsigned)
                    x16[(size_t)((unsigned)ea.x & 0xFFFFu) * DFEAT + lane] << 16);
                xb[k] = __uint_as_float((unsigned)
                    x16[(size_t)((unsigned)eb.x & 0xFFFFu) * DFEAT + lane] << 16);
            }
            #pragma unroll
            for (int k = 0; k < 8; k++) {
                accA += va[k] * xa[k];
                accB += vb[k] * xb[k];
            }
        }
        size_t goA = (size_t)(p * RPB + rA) * DFEAT + lane;
        size_t goB = (size_t)(p * RPB + rB) * DFEAT + lane;
        out[goA] = accA + x0[goA] + bl;          // coalesced 256 B row store
        out[goB] = accB + x0[goB] + bl;
    }
}

// Drain per-region overflow lists with full-precision f32 x. Runs AFTER spmm.
__global__ void ov_drain_kernel(const float* __restrict__ x,
                                const int* __restrict__ ov_cnt,
                                const int2* __restrict__ ov,
                                float* __restrict__ out,
                                int NP, int epb) {
    int wid = (blockIdx.x * blockDim.x + threadIdx.x) >> 6;
    int lane = threadIdx.x & 63;
    int nw = (gridDim.x * blockDim.x) >> 6;
    int regions = BBLK + NP;
    for (int reg = wid; reg < regions; reg += nw) {
        int n = ov_cnt[reg];
        size_t rbase;
        int cap;
        if (reg < BBLK) { rbase = (size_t)reg * epb; cap = epb; }
        else {
            rbase = (size_t)BBLK * epb + (size_t)(reg - BBLK) * OVS_S;
            cap = OVS_S;
        }
        if (n > cap) n = cap;
        for (int k = 0; k < n; k++) {
            int2 pk = ov[rbase + k];
            unsigned ux = (unsigned)pk.x;
            int r = (int)(ux >> 16);
            int c = (int)(ux & 0xFFFFu);
            float v = __int_as_float(pk.y);
            atomicAdd(&out[(size_t)r * DFEAT + lane],
                      v * x[(size_t)c * DFEAT + lane]);
        }
    }
}

// ---------------- R7 single-phase path (general N; medium ws) ---------------

__global__ void bucket_scatter_kernel(const int* __restrict__ edge_row,
                                      const int* __restrict__ edge_col,
                                      const float* __restrict__ edge_val,
                                      int* __restrict__ cursor,
                                      int2* __restrict__ bucket,
                                      int* __restrict__ ov_cursor,
                                      int* __restrict__ ov_list,
                                      int E, int C) {
    int e = blockIdx.x * blockDim.x + threadIdx.x;
    if (e >= E) return;
    int r = edge_row[e];
    int pos = atomicAdd(&cursor[r], 1);
    if (pos < C) {
        int2 ent;
        ent.x = edge_col[e];
        ent.y = __float_as_int(edge_val[e]);
        bucket[(size_t)r * C + pos] = ent;
    } else {
        int op = atomicAdd(ov_cursor, 1);
        ov_list[op] = e;
    }
}

__global__ __launch_bounds__(256) void spmm_kernel(
        const float* __restrict__ x,
        const float* __restrict__ x0,
        const float* __restrict__ bias,
        const int* __restrict__ counts,
        const int2* __restrict__ bucket,
        float* __restrict__ out, int n, int C) {
    int wid = (blockIdx.x * blockDim.x + threadIdx.x) >> 6;
    int lane = threadIdx.x & 63;
    if (wid >= n) return;
    int cnt = counts[wid];
    if (cnt > C) cnt = C;
    const int2* bk = bucket + (size_t)wid * C;
    float acc = 0.f;
    for (int s0 = 0; s0 < cnt; s0 += 64) {
        int m = cnt - s0; if (m > 64) m = 64;
        int c = 0; float v = 0.f;
        if (lane < m) {
            int2 p = bk[s0 + lane];
            c = p.x;
            v = __int_as_float(p.y);
        }
        for (int j0 = 0; j0 < m; j0 += 8) {
            float xv[8], vv[8];
            #pragma unroll
            for (int k = 0; k < 8; k++) {
                int cj = __builtin_amdgcn_readlane(c, j0 + k);
                int vb = __builtin_amdgcn_readlane(__float_as_int(v), j0 + k);
                vv[k] = __int_as_float(vb);
                xv[k] = x[(size_t)cj * DFEAT + lane];
            }
            #pragma unroll
            for (int k = 0; k < 8; k++)
                acc += vv[k] * xv[k];
        }
    }
    out[(size_t)wid * DFEAT + lane] =
        acc + x0[(size_t)wid * DFEAT + lane] + bias[lane];
}

__global__ void ov_drain_id_kernel(const int* __restrict__ edge_row,
                                   const int* __restrict__ edge_col,
                                   const float* __restrict__ edge_val,
                                   const float* __restrict__ x,
                                   const int* __restrict__ ov_cursor,
                                   const int* __restrict__ ov_list,
                                   float* __restrict__ out, int E) {
    int n = ov_cursor[0];
    if (n > E) n = E;
    int wid = (blockIdx.x * blockDim.x + threadIdx.x) >> 6;
    int lane = threadIdx.x & 63;
    int nw = (gridDim.x * blockDim.x) >> 6;
    for (int k = wid; k < n; k += nw) {
        int e = ov_list[k];
        int r = edge_row[e], c = edge_col[e];
        float v = edge_val[e];
        atomicAdd(&out[(size_t)r * DFEAT + lane],
                  v * x[(size_t)c * DFEAT + lane]);
    }
}

// ---------------- last-resort fallback (round-1 structure) ------------------

__global__ void init_out_kernel(const float* __restrict__ x0,
                                const float* __restrict__ bias,
                                float* __restrict__ out, int n4) {
    int i = blockIdx.x * blockDim.x + threadIdx.x;
    if (i < n4) {
        float4 v = ((const float4*)x0)[i];
        int d = (i * 4) & (DFEAT - 1);
        v.x += bias[d + 0]; v.y += bias[d + 1];
        v.z += bias[d + 2]; v.w += bias[d + 3];
        ((float4*)out)[i] = v;
    }
}

__global__ void edge_scatter_kernel(const float* __restrict__ x,
                                    const float* __restrict__ edge_val,
                                    const int* __restrict__ edge_row,
                                    const int* __restrict__ edge_col,
                                    float* __restrict__ out, int E) {
    int tid = blockIdx.x * blockDim.x + threadIdx.x;
    int wave = tid >> 6, lane = tid & 63;
    int nwaves = (gridDim.x * blockDim.x) >> 6;
    for (int e = wave; e < E; e += nwaves) {
        int row = edge_row[e];
        int col = edge_col[e];
        float val = edge_val[e];
        atomicAdd(&out[row * DFEAT + lane], val * x[col * DFEAT + lane]);
    }
}

extern "C" void kernel_launch(void* const* d_in, const int* in_sizes, int n_in,
                              void* d_out, int out_size, void* d_ws, size_t ws_size,
                              hipStream_t stream) {
    const float* x    = (const float*)d_in[0];
    const float* x0   = (const float*)d_in[1];
    const float* ev   = (const float*)d_in[2];
    // d_in[3] = weight: unused (Cayley == identity)
    const float* bias = (const float*)d_in[4];
    const int*   er   = (const int*)d_in[5];
    const int*   ec   = (const int*)d_in[6];
    float* out = (float*)d_out;

    int E = in_sizes[2];
    int N = out_size / DFEAT;

    auto align256 = [](size_t b) { return (b + 255) & ~size_t(255); };

    // ---- Round-16 path ----
    if (N <= 65536 && N % RPB == 0 && E > 0) {
        int NP = N / RPB;                       // partitions (<= 1024)
        int epb = (E + BBLK - 1) / BBLK;        // 8192 for E=1M

        size_t ovc_b  = align256((size_t)(BBLK + NP) * 4);
        size_t x16_b  = align256((size_t)N * DFEAT * 2);
        size_t ov_b   = align256(((size_t)BBLK * epb + (size_t)NP * OVS_S) * 8);
        size_t sl_b   = align256((size_t)NP * BBLK * CELL_I2 * 8);
        size_t total  = ovc_b + x16_b + ov_b + sl_b;
        size_t smem_b = (size_t)NP * 128 + (size_t)(NP + 1) * 4;

        if (total <= ws_size && smem_b <= 160 * 1024) {
            char* ws = (char*)d_ws;
            int*            ovc    = (int*)ws;
            unsigned short* x16    = (unsigned short*)(ws + ovc_b);
            int2*           ovl    = (int2*)(ws + ovc_b + x16_b);
            int2*           slists = (int2*)(ws + ovc_b + x16_b + ov_b);

            int n4 = N * DFEAT / 4;
            build_conv_kernel<<<BBLK + CONV_BLK, BUILD_T, smem_b, stream>>>(
                er, ec, ev, x, x16, slists, ovc, ovl, E, NP, epb, n4);
            spmm_fused_kernel<<<NP, SPMM_T, 0, stream>>>(
                x16, x0, bias, slists, ovc, ovl, out, NP, epb);
            ov_drain_kernel<<<256, 256, 0, stream>>>(
                x, ovc, ovl, out, NP, epb);
            return;
        }
    }

    // ---- R7 single-phase path ----
    {
        size_t cur_b = align256((size_t)N * 4);
        size_t ovc_b = 256;
        size_t ov_b  = align256((size_t)E * 4);
        size_t fixed = cur_b + ovc_b + ov_b;
        int C = 0;
        if (ws_size > fixed) {
            long long cmax = (long long)((ws_size - fixed) / ((size_t)N * 8));
            for (int cand : {64, 48, 40, 32, 28, 24})
                if (cmax >= cand) { C = cand; break; }
        }
        if (C >= 24) {
            char* ws = (char*)d_ws;
            int*  cursor  = (int*)ws;
            int*  ovc     = (int*)(ws + cur_b);
            int*  ov_list = (int*)(ws + cur_b + ovc_b);
            int2* bucket  = (int2*)(ws + fixed);

            int nzero = (int)((cur_b + ovc_b) / 4);
            zero_ints_kernel<<<(nzero + 255) / 256, 256, 0, stream>>>(cursor, nzero);
            bucket_scatter_kernel<<<(E + 255) / 256, 256, 0, stream>>>(
                er, ec, ev, cursor, bucket, ovc, ov_list, E, C);
            int blocks = (N * 64 + 255) / 256;
            spmm_kernel<<<blocks, 256, 0, stream>>>(
                x, x0, bias, cursor, bucket, out, N, C);
            ov_drain_id_kernel<<<64, 256, 0, stream>>>(
                er, ec, ev, x, ovc, ov_list, out, E);
            return;
        }
    }

    // ---- last resort: atomic scatter ----
    int n4 = out_size / 4;
    init_out_kernel<<<(n4 + 255) / 256, 256, 0, stream>>>(x0, bias, out, n4);
    edge_scatter_kernel<<<8192, 256, 0, stream>>>(x, ev, er, ec, out, E);
}